// Round 5
// baseline (201.169 us; speedup 1.0000x reference)
//
#include <hip/hip_runtime.h>

#define DD 768
#define P 196
#define PP 224            // rows per image in workspace
#define NIMG 64
#define NN 32
#define MARGIN 0.5f
#define NCH 24            // K-chunks of 32 elements
#define PIECES 896        // 224 rows * 4 pieces (16 B) per chunk per matrix
#define BPIECES 448       // 112 rows * 4 pieces : the staged B half
#define NINSTR 21         // (896 + 448) / 64 DMA instructions per chunk

typedef __bf16 bf16;
typedef __bf16 bf16x8 __attribute__((ext_vector_type(8)));   // 16 B MFMA A/B frag
typedef float floatx4 __attribute__((ext_vector_type(4)));   // 16x16 MFMA C/D frag

typedef __attribute__((address_space(1))) const unsigned char g_u8;
typedef __attribute__((address_space(3))) unsigned char l_u8;

// Workspace Y layout (chunk-major, swizzled):
//   piece(img, c, r, kg') at flat uint4 index (img*24 + c)*896 + r*4 + kg'
//   data piece kg (k = c*32 + kg*8 ..) stored at kg' = kg ^ ((r>>1)&3)
// Staging a chunk (or a q-half of one) is a contiguous lane-linear block
// (matches global_load_lds wave-uniform-base + lane*16), and ds_read_b128
// frag reads hit each bank exactly twice per 16-lane phase (conflict-free,
// verified R4: SQ_LDS_BANK_CONFLICT == 0).

// ---------------------------------------------------------------------------
// Kernel 1: 8 waves/block, one row per wave (8 consecutive rows of one image).
// Normalize in registers, buffer the bf16 row in LDS, then write out
// chunk-major in 512-B contiguous segments (R4 wrote scattered 16-B pieces).
// Pad rows (p>=196) are skipped: the 0xAA ws poison is a tiny finite bf16 and
// every consumer masks those rows/cols. Also zero-inits the scalar output.
// ---------------------------------------------------------------------------
__global__ __launch_bounds__(512) void norm_kernel(const float* __restrict__ nrm,
                                                   const float* __restrict__ dft,
                                                   bf16* __restrict__ Y,
                                                   float* __restrict__ out) {
    if (blockIdx.x == 0 && threadIdx.x == 0) out[0] = 0.0f;
    __shared__ uint4 rowbuf[8][97];              // 96 pieces/row, +1 pad

    int img = blockIdx.x / 28;
    int rg  = blockIdx.x % 28;                   // 8-row group
    int wave = threadIdx.x >> 6;
    int lane = threadIdx.x & 63;
    int p = rg * 8 + wave;

    if (p < P) {
        const float* src = (img < NN) ? nrm + ((size_t)img * P + p) * DD
                                      : dft + ((size_t)(img - NN) * P + p) * DD;
        float4 a0 = *(const float4*)(src + lane * 8);
        float4 a1 = *(const float4*)(src + lane * 8 + 4);
        float4 b0 = {0,0,0,0}, b1 = {0,0,0,0};
        float ss = a0.x*a0.x + a0.y*a0.y + a0.z*a0.z + a0.w*a0.w
                 + a1.x*a1.x + a1.y*a1.y + a1.z*a1.z + a1.w*a1.w;
        if (lane < 32) {
            b0 = *(const float4*)(src + 512 + lane * 8);
            b1 = *(const float4*)(src + 512 + lane * 8 + 4);
            ss += b0.x*b0.x + b0.y*b0.y + b0.z*b0.z + b0.w*b0.w
                + b1.x*b1.x + b1.y*b1.y + b1.z*b1.z + b1.w*b1.w;
        }
        #pragma unroll
        for (int o = 32; o > 0; o >>= 1) ss += __shfl_xor(ss, o);
        float inv = 1.0f / (sqrtf(ss) + 1e-8f);

        auto cvt = [&](float4 x0, float4 x1) {
            bf16x8 w;
            w[0] = (bf16)(x0.x*inv); w[1] = (bf16)(x0.y*inv);
            w[2] = (bf16)(x0.z*inv); w[3] = (bf16)(x0.w*inv);
            w[4] = (bf16)(x1.x*inv); w[5] = (bf16)(x1.y*inv);
            w[6] = (bf16)(x1.z*inv); w[7] = (bf16)(x1.w*inv);
            union { bf16x8 h; uint4 u; } cv; cv.h = w; return cv.u;
        };
        rowbuf[wave][lane] = cvt(a0, a1);                       // pieces 0..63
        if (lane < 32) rowbuf[wave][64 + lane] = cvt(b0, b1);   // pieces 64..95
    }
    __syncthreads();

    // write-out: piece idx = c*32 + r*4 + kgp  ->  512-B contiguous per (c)
    for (int idx = threadIdx.x; idx < 768; idx += 512) {
        int c = idx >> 5, r = (idx >> 2) & 7, kgp = idx & 3;
        int pr = rg * 8 + r;
        if (pr >= P) continue;
        int kg = kgp ^ ((pr >> 1) & 3);
        *(uint4*)(Y + ((size_t)(img * NCH + c) * PIECES + pr * 4 + kgp) * 8) =
            rowbuf[r][c * 4 + kg];
    }
}

// ---------------------------------------------------------------------------
// Kernel 2: TWO blocks per pair (q-halves of 112), 256 threads = 4 waves.
// Wave w: p-rows [w*64, w*64+63] (p padded to 256; pad subtile reads clamp to
// row 223 -> LDS broadcast, masked in epilogue), all 112 q of this half.
// Wave tile = 4x7 of 16x16x32 MFMA, acc = 112 regs. LDS 43 KB -> 2 blocks/CU
// co-resident: independent barriers overlap each other's DMA-drain stalls.
// ---------------------------------------------------------------------------
__global__ __launch_bounds__(256, 2) void pair_kernel(const bf16* __restrict__ Y,
                                                      float* __restrict__ out) {
    __shared__ uint4 tiles[2][PIECES + BPIECES];   // [buf][A | B-half] = 42 KB
    __shared__ float colmax[4][112];
    __shared__ float redp[4];

    int bx = blockIdx.x;
    int b  = bx >> 1;                // pair index
    int qh = bx & 1;                 // q-half
    int ia, ja; bool is_nn;
    if (b < 496) {
        is_nn = true;
        int i = 0, rem = b;
        while (rem >= 31 - i) { rem -= 31 - i; ++i; }   // triangular, i<j
        ia = i; ja = i + 1 + rem;
    } else {
        is_nn = false;
        int t = b - 496;
        ia = t & 31; ja = NN + (t >> 5);
    }

    int tid  = threadIdx.x;
    int lane = tid & 63;
    int wave = tid >> 6;             // 0..3 : p-strip of 64
    int r16  = lane & 15;
    int quad = lane >> 4;            // 0..3 : k-group of 8

    floatx4 acc[4][7];
    #pragma unroll
    for (int ps = 0; ps < 4; ++ps)
        #pragma unroll
        for (int t = 0; t < 7; ++t)
            acc[ps][t] = (floatx4){0.f, 0.f, 0.f, 0.f};

    // A-frag LDS piece offsets (clamped rows -> broadcast reads, masked later)
    int aoff[4];
    #pragma unroll
    for (int ps = 0; ps < 4; ++ps) {
        int pr = wave * 64 + ps * 16 + r16;
        if (pr > PP - 1) pr = PP - 1;
        aoff[ps] = pr * 4 + (quad ^ ((pr >> 1) & 3));
    }
    int boff[7];
    #pragma unroll
    for (int t = 0; t < 7; ++t) {
        int ql = t * 16 + r16;
        boff[t] = PIECES + ql * 4 + (quad ^ ((ql >> 1) & 3));
    }

    // stage chunk c (A full + B q-half) into buffer buf: 21 DMA instructions
    auto stage = [&](int buf, int c) {
        const bf16* gA = Y + (size_t)(ia * NCH + c) * (PIECES * 8);
        const bf16* gB = Y + ((size_t)(ja * NCH + c) * PIECES + qh * BPIECES) * 8;
        #pragma unroll
        for (int u = 0; u < 6; ++u) {
            int i = wave + 4 * u;
            if (i >= NINSTR) break;
            const bf16* g = (i < 14) ? gA + (size_t)(i * 64 + lane) * 8
                                     : gB + (size_t)((i - 14) * 64 + lane) * 8;
            __builtin_amdgcn_global_load_lds((const g_u8*)g,
                                             (l_u8*)&tiles[buf][i * 64], 16, 0, 0);
        }
    };

    stage(0, 0);
    for (int c = 0; c < NCH; ++c) {
        __syncthreads();             // drains DMA for chunk c; frees other buf
        const uint4* tb = tiles[c & 1];
        bf16x8 afr[4], bfr[7];
        #pragma unroll
        for (int ps = 0; ps < 4; ++ps) afr[ps] = *(const bf16x8*)(tb + aoff[ps]);
        #pragma unroll
        for (int t = 0; t < 7; ++t)   bfr[t]  = *(const bf16x8*)(tb + boff[t]);
        if (c + 1 < NCH) stage((c + 1) & 1, c + 1);  // in flight across MFMAs
        #pragma unroll
        for (int ps = 0; ps < 4; ++ps)
            #pragma unroll
            for (int t = 0; t < 7; ++t)
                acc[ps][t] = __builtin_amdgcn_mfma_f32_16x16x32_bf16(
                    afr[ps], bfr[t], acc[ps][t], 0, 0, 0);
    }

    // column-max over valid p (<196) per q. C/D: col q = lane&15, row = quad*4+r
    #pragma unroll
    for (int t = 0; t < 7; ++t) {
        float m = -3.0e38f;
        #pragma unroll
        for (int ps = 0; ps < 4; ++ps) {
            int pbase = wave * 64 + ps * 16 + quad * 4;
            #pragma unroll
            for (int r = 0; r < 4; ++r)
                if (pbase + r < P) m = fmaxf(m, acc[ps][t][r]);
        }
        m = fmaxf(m, __shfl_xor(m, 16));
        m = fmaxf(m, __shfl_xor(m, 32));
        if (quad == 0) colmax[wave][t * 16 + r16] = m;
    }
    __syncthreads();

    float contrib = 0.f;
    if (tid < 112 && qh * 112 + tid < P) {       // q >= 196 are pad cols
        float cm = fmaxf(fmaxf(colmax[0][tid], colmax[1][tid]),
                         fmaxf(colmax[2][tid], colmax[3][tid]));
        contrib = is_nn ? (1.0f - cm) * (1.0f / (496.0f * 196.0f))
                        : fmaxf(cm - MARGIN, 0.0f) * (1.0f / (1024.0f * 196.0f));
    }
    #pragma unroll
    for (int o = 32; o > 0; o >>= 1) contrib += __shfl_down(contrib, o);
    if (lane == 0) redp[wave] = contrib;
    __syncthreads();
    if (tid == 0)
        atomicAdd(out, redp[0] + redp[1] + redp[2] + redp[3]);
}

// ---------------------------------------------------------------------------
extern "C" void kernel_launch(void* const* d_in, const int* in_sizes, int n_in,
                              void* d_out, int out_size, void* d_ws, size_t ws_size,
                              hipStream_t stream) {
    const float* nrm = (const float*)d_in[0];   // [32,196,768] fp32
    const float* dft = (const float*)d_in[1];   // [32,196,768] fp32
    float* out = (float*)d_out;                 // scalar fp32
    bf16* Y = (bf16*)d_ws;                      // [64][24][896] uint4 pieces = 22 MB

    norm_kernel<<<NIMG * 28, 512, 0, stream>>>(nrm, dft, Y, out);
    pair_kernel<<<2 * (496 + 1024), 256, 0, stream>>>(Y, out);
}

// Round 6
// 200.732 us; speedup vs baseline: 1.0022x; 1.0022x over previous
//
#include <hip/hip_runtime.h>

#define DD 768
#define P 196
#define PP 224            // rows per image in workspace
#define NIMG 64
#define NN 32
#define MARGIN 0.5f
#define NCH 24            // K-chunks of 32 elements
#define APIECES 896       // A: 224 rows * 4 pieces(16B) per chunk
#define BPIECES 448       // B q-half: 112 rows * 4 pieces
#define TPB (APIECES + BPIECES)        // 1344 pieces per buffer
#define BUFB (TPB * 16)                // 21504 bytes per buffer
#define CHELEM 7168                    // bf16 elems per image-chunk (896*8)

typedef __bf16 bf16;
typedef __bf16 bf16x8 __attribute__((ext_vector_type(8)));   // 16 B MFMA A/B frag
typedef float floatx4 __attribute__((ext_vector_type(4)));   // 16x16 MFMA C/D frag

typedef __attribute__((address_space(1))) const unsigned char g_u8;
typedef __attribute__((address_space(3))) unsigned char l_u8;

// Workspace Y layout (chunk-major, swizzled) — unchanged from R4/R5 (verified):
//   piece(img, c, r, kg') at flat uint4 index (img*24 + c)*896 + r*4 + kg'
//   data piece kg stored at kg' = kg ^ ((r>>1)&3)

// ---------------------------------------------------------------------------
// Kernel 1 (unchanged from R5): 8 waves/block, one row per wave. Normalize in
// registers, buffer bf16 row in LDS, write out chunk-major in 512-B segments.
// Pad rows (p>=196) keep the 0xAA poison (finite bf16, masked in consumers).
// ---------------------------------------------------------------------------
__global__ __launch_bounds__(512) void norm_kernel(const float* __restrict__ nrm,
                                                   const float* __restrict__ dft,
                                                   bf16* __restrict__ Y,
                                                   float* __restrict__ out) {
    if (blockIdx.x == 0 && threadIdx.x == 0) out[0] = 0.0f;
    __shared__ uint4 rowbuf[8][97];

    int img = blockIdx.x / 28;
    int rg  = blockIdx.x % 28;
    int wave = threadIdx.x >> 6;
    int lane = threadIdx.x & 63;
    int p = rg * 8 + wave;

    if (p < P) {
        const float* src = (img < NN) ? nrm + ((size_t)img * P + p) * DD
                                      : dft + ((size_t)(img - NN) * P + p) * DD;
        float4 a0 = *(const float4*)(src + lane * 8);
        float4 a1 = *(const float4*)(src + lane * 8 + 4);
        float4 b0 = {0,0,0,0}, b1 = {0,0,0,0};
        float ss = a0.x*a0.x + a0.y*a0.y + a0.z*a0.z + a0.w*a0.w
                 + a1.x*a1.x + a1.y*a1.y + a1.z*a1.z + a1.w*a1.w;
        if (lane < 32) {
            b0 = *(const float4*)(src + 512 + lane * 8);
            b1 = *(const float4*)(src + 512 + lane * 8 + 4);
            ss += b0.x*b0.x + b0.y*b0.y + b0.z*b0.z + b0.w*b0.w
                + b1.x*b1.x + b1.y*b1.y + b1.z*b1.z + b1.w*b1.w;
        }
        #pragma unroll
        for (int o = 32; o > 0; o >>= 1) ss += __shfl_xor(ss, o);
        float inv = 1.0f / (sqrtf(ss) + 1e-8f);

        auto cvt = [&](float4 x0, float4 x1) {
            bf16x8 w;
            w[0] = (bf16)(x0.x*inv); w[1] = (bf16)(x0.y*inv);
            w[2] = (bf16)(x0.z*inv); w[3] = (bf16)(x0.w*inv);
            w[4] = (bf16)(x1.x*inv); w[5] = (bf16)(x1.y*inv);
            w[6] = (bf16)(x1.z*inv); w[7] = (bf16)(x1.w*inv);
            union { bf16x8 h; uint4 u; } cv; cv.h = w; return cv.u;
        };
        rowbuf[wave][lane] = cvt(a0, a1);
        if (lane < 32) rowbuf[wave][64 + lane] = cvt(b0, b1);
    }
    __syncthreads();

    for (int idx = threadIdx.x; idx < 768; idx += 512) {
        int c = idx >> 5, r = (idx >> 2) & 7, kgp = idx & 3;
        int pr = rg * 8 + r;
        if (pr >= P) continue;
        int kg = kgp ^ ((pr >> 1) & 3);
        *(uint4*)(Y + ((size_t)(img * NCH + c) * APIECES + pr * 4 + kgp) * 8) =
            rowbuf[r][c * 4 + kg];
    }
}

// ---------------------------------------------------------------------------
// Kernel 2: two blocks per pair (q-halves), 256 threads = 4 waves.
// Waves 0-2: p-rows [w*64, w*64+63] (4 subtiles); wave 3: rows 192..207
// (1 subtile; valid p 192..195) -> 13 p-subtiles total, no garbage compute.
// Triple-buffered BK=32 staging via global_load_lds; raw s_barrier + manual
// s_waitcnt vmcnt(N) keeps the next chunk's DMA in flight across ~2 chunk
// bodies (never drains to 0 mid-loop). All ds_read addresses are constant
// offsets from 2 base pointers (swizzle is ps/t-invariant).
// ---------------------------------------------------------------------------
__global__ __launch_bounds__(256, 2) void pair_kernel(const bf16* __restrict__ Y,
                                                      float* __restrict__ out) {
    __shared__ uint4 tiles[3 * TPB];   // 64512 B (colmax aliased in epilogue)
    __shared__ float redp[4];

    int bx = blockIdx.x;
    int b  = bx >> 1;                // pair index
    int qh = bx & 1;                 // q-half
    int ia, ja; bool is_nn;
    if (b < 496) {
        is_nn = true;
        int i = 0, rem = b;
        while (rem >= 31 - i) { rem -= 31 - i; ++i; }   // triangular, i<j
        ia = i; ja = i + 1 + rem;
    } else {
        is_nn = false;
        int t = b - 496;
        ia = t & 31; ja = NN + (t >> 5);
    }

    int tid  = threadIdx.x;
    int lane = tid & 63;
    int wave = tid >> 6;             // 0..3
    int r16  = lane & 15;
    int quad = lane >> 4;            // 0..3 : k-group of 8
    int sw   = quad ^ ((r16 >> 1) & 3);   // XOR swizzle (row-invariant mod 16)

    // constant-offset frag base pointers (all further addressing is immediates)
    const char* abp = (const char*)tiles + wave * 4096 + (r16 * 4 + sw) * 16;
    const char* bbp = (const char*)tiles + APIECES * 16 + (r16 * 4 + sw) * 16;

    floatx4 acc[4][7];
    #pragma unroll
    for (int ps = 0; ps < 4; ++ps)
        #pragma unroll
        for (int t = 0; t < 7; ++t)
            acc[ps][t] = (floatx4){0.f, 0.f, 0.f, 0.f};

    // 21 DMA instrs/chunk: i<14 = A pieces, i>=14 = B-half pieces.
    // waves issue i = wave+4u (u<5) -> i 0..19; wave 0 also issues i=20.
    l_u8* lds0 = (l_u8*)&tiles[0];
    auto stage = [&](const bf16* ga, const bf16* gb, l_u8* ldsb) {
        #pragma unroll
        for (int u = 0; u < 5; ++u) {
            int i = wave + 4 * u;
            const bf16* g = (i < 14) ? ga + (i * 64 + lane) * 8
                                     : gb + ((i - 14) * 64 + lane) * 8;
            __builtin_amdgcn_global_load_lds((const g_u8*)g, ldsb + i * 1024, 16, 0, 0);
        }
        if (wave == 0)
            __builtin_amdgcn_global_load_lds((const g_u8*)(gb + (6 * 64 + lane) * 8),
                                             ldsb + 20 * 1024, 16, 0, 0);
    };

    const bf16* gA = Y + (size_t)ia * (NCH * CHELEM);
    const bf16* gB = Y + (size_t)ja * (NCH * CHELEM) + qh * (BPIECES * 8);
    stage(gA, gB, lds0);            gA += CHELEM; gB += CHELEM;
    stage(gA, gB, lds0 + BUFB);     gA += CHELEM; gB += CHELEM;

    for (int cb = 0; cb < NCH; cb += 3) {
        #pragma unroll
        for (int cc = 0; cc < 3; ++cc) {
            int c = cb + cc;
            // wait for chunk c's DMAs only (leave chunk c+1's in flight);
            // vmcnt simm16: lgkm=0xF<<8 | exp=0x7<<4 | vm low4
            if (c == NCH - 1)    __builtin_amdgcn_s_waitcnt(0xF70);  // vmcnt(0)
            else if (wave == 0)  __builtin_amdgcn_s_waitcnt(0xF76);  // vmcnt(6)
            else                 __builtin_amdgcn_s_waitcnt(0xF75);  // vmcnt(5)
            __builtin_amdgcn_s_barrier();
            __builtin_amdgcn_sched_barrier(0);   // pin: no ds_read above barrier

            bf16x8 afr[4], bfr[7];
            afr[0] = *(const bf16x8*)(abp + cc * BUFB);
            if (wave < 3) {
                afr[1] = *(const bf16x8*)(abp + cc * BUFB + 1024);
                afr[2] = *(const bf16x8*)(abp + cc * BUFB + 2048);
                afr[3] = *(const bf16x8*)(abp + cc * BUFB + 3072);
            }
            #pragma unroll
            for (int t = 0; t < 7; ++t)
                bfr[t] = *(const bf16x8*)(bbp + cc * BUFB + t * 1024);

            if (c + 2 < NCH) {
                stage(gA, gB, lds0 + ((cc + 2) % 3) * BUFB);
                gA += CHELEM; gB += CHELEM;
            }

            #pragma unroll
            for (int t = 0; t < 7; ++t)
                acc[0][t] = __builtin_amdgcn_mfma_f32_16x16x32_bf16(
                    afr[0], bfr[t], acc[0][t], 0, 0, 0);
            if (wave < 3) {
                #pragma unroll
                for (int ps = 1; ps < 4; ++ps)
                    #pragma unroll
                    for (int t = 0; t < 7; ++t)
                        acc[ps][t] = __builtin_amdgcn_mfma_f32_16x16x32_bf16(
                            afr[ps], bfr[t], acc[ps][t], 0, 0, 0);
            }
        }
    }

    __syncthreads();                 // all tile reads done; alias as colmax
    float* colmax = (float*)tiles;   // [4][112]

    // C/D: col q = lane&15, row p = quad*4 + r (within subtile)
    #pragma unroll
    for (int t = 0; t < 7; ++t) {
        float m = -3.0e38f;
        #pragma unroll
        for (int ps = 0; ps < 4; ++ps) {
            int pbase = wave * 64 + ps * 16 + quad * 4;
            #pragma unroll
            for (int r = 0; r < 4; ++r)
                if (pbase + r < P) m = fmaxf(m, acc[ps][t][r]);
        }
        m = fmaxf(m, __shfl_xor(m, 16));
        m = fmaxf(m, __shfl_xor(m, 32));
        if (quad == 0) colmax[wave * 112 + t * 16 + r16] = m;
    }
    __syncthreads();

    float contrib = 0.f;
    if (tid < 112 && qh * 112 + tid < P) {
        float cm = fmaxf(fmaxf(colmax[tid], colmax[112 + tid]),
                         fmaxf(colmax[224 + tid], colmax[336 + tid]));
        contrib = is_nn ? (1.0f - cm) * (1.0f / (496.0f * 196.0f))
                        : fmaxf(cm - MARGIN, 0.0f) * (1.0f / (1024.0f * 196.0f));
    }
    #pragma unroll
    for (int o = 32; o > 0; o >>= 1) contrib += __shfl_down(contrib, o);
    if (lane == 0) redp[wave] = contrib;
    __syncthreads();
    if (tid == 0)
        atomicAdd(out, redp[0] + redp[1] + redp[2] + redp[3]);
}

// ---------------------------------------------------------------------------
extern "C" void kernel_launch(void* const* d_in, const int* in_sizes, int n_in,
                              void* d_out, int out_size, void* d_ws, size_t ws_size,
                              hipStream_t stream) {
    const float* nrm = (const float*)d_in[0];   // [32,196,768] fp32
    const float* dft = (const float*)d_in[1];   // [32,196,768] fp32
    float* out = (float*)d_out;                 // scalar fp32
    bf16* Y = (bf16*)d_ws;                      // [64][24][896] uint4 pieces = 22 MB

    norm_kernel<<<NIMG * 28, 512, 0, stream>>>(nrm, dft, Y, out);
    pair_kernel<<<2 * (496 + 1024), 256, 0, stream>>>(Y, out);
}

// Round 8
// 168.216 us; speedup vs baseline: 1.1959x; 1.1933x over previous
//
#include <hip/hip_runtime.h>
#include <hip/hip_fp8.h>

#define P 196
#define NN 32
#define MARGIN 0.5f
#define NCH 12            // K-chunks of 64 fp8 elements
#define APIECES 896       // A: 224 rows * 4 pieces (16 B) per chunk
#define BPIECES 448       // B q-half: 112 rows * 4 pieces
#define TPB (APIECES + BPIECES)        // 1344 pieces per buffer
#define BUFB (TPB * 16)                // 21504 bytes per buffer
#define CHB (APIECES * 16)             // 14336 bytes per image-chunk

typedef long longx2 __attribute__((ext_vector_type(2)));     // 16 B = 2 fp8 half-frags
typedef float floatx4 __attribute__((ext_vector_type(4)));   // 16x16 MFMA C/D frag

typedef __attribute__((address_space(1))) const unsigned char g_u8;
typedef __attribute__((address_space(3))) unsigned char l_u8;

// Workspace Y layout (fp8 e4m3, chunk-major, swizzled):
//   chunk c covers k = c*64 .. c*64+63. Piece(img,c,r,kg') = 16 B at
//   (img*12 + c)*14336 + (r*4 + kg')*16, with kg' = kg ^ ((r>>1)&3).
//   Piece bytes 0-7  = fp8 for k_local in [kg*8, kg*8+8)       (s=0)
//   Piece bytes 8-15 = fp8 for k_local in [32+kg*8, 32+kg*8+8) (s=1)
//   -> one ds_read_b128 yields the A/B half-frags (long lo/hi) for TWO
//      16x16x32 MFMAs. Piece geometry identical to R6 (HW-verified
//      conflict-free and in-bounds).

// ---------------------------------------------------------------------------
// Kernel 1: 8 waves/block, one row per wave. fp32 normalize in registers,
// convert to OCP fp8 e4m3 via __hip_fp8_e4m3 (library-supported on gfx950;
// replaces the R7 cvt builtin — the only unproven instruction in the R7
// crash), buffer the row in LDS, write chunk-major in 512-B segments.
// Pad rows (p>=196) keep the 0xAA ws poison (finite fp8, masked in consumers).
// Also zero-inits the scalar output.
// ---------------------------------------------------------------------------
__global__ __launch_bounds__(512) void norm_kernel(const float* __restrict__ nrm,
                                                   const float* __restrict__ dft,
                                                   unsigned char* __restrict__ Y,
                                                   float* __restrict__ out) {
    if (blockIdx.x == 0 && threadIdx.x == 0) out[0] = 0.0f;
    __shared__ uint2 rowbuf[8][100];             // 96 groups of 8 fp8 per row

    int img  = blockIdx.x / 28;
    int rg   = blockIdx.x % 28;
    int wave = threadIdx.x >> 6;
    int lane = threadIdx.x & 63;
    int p = rg * 8 + wave;

    if (p < P) {
        const float* src = (img < NN) ? nrm + ((size_t)img * P + p) * 768
                                      : dft + ((size_t)(img - NN) * P + p) * 768;
        float4 a0 = *(const float4*)(src + lane * 8);
        float4 a1 = *(const float4*)(src + lane * 8 + 4);
        float4 b0 = {0,0,0,0}, b1 = {0,0,0,0};
        float ss = a0.x*a0.x + a0.y*a0.y + a0.z*a0.z + a0.w*a0.w
                 + a1.x*a1.x + a1.y*a1.y + a1.z*a1.z + a1.w*a1.w;
        if (lane < 32) {
            b0 = *(const float4*)(src + 512 + lane * 8);
            b1 = *(const float4*)(src + 512 + lane * 8 + 4);
            ss += b0.x*b0.x + b0.y*b0.y + b0.z*b0.z + b0.w*b0.w
                + b1.x*b1.x + b1.y*b1.y + b1.z*b1.z + b1.w*b1.w;
        }
        #pragma unroll
        for (int o = 32; o > 0; o >>= 1) ss += __shfl_xor(ss, o);
        float inv = 1.0f / (sqrtf(ss) + 1e-8f);

        auto q8 = [&](float f) -> unsigned {     // fp32 -> OCP e4m3 byte
            return (unsigned)__hip_fp8_e4m3(f).__x;
        };
        auto pack8 = [&](float4 x0, float4 x1) {
            uint2 g;
            g.x = q8(x0.x*inv) | (q8(x0.y*inv) << 8) |
                  (q8(x0.z*inv) << 16) | (q8(x0.w*inv) << 24);
            g.y = q8(x1.x*inv) | (q8(x1.y*inv) << 8) |
                  (q8(x1.z*inv) << 16) | (q8(x1.w*inv) << 24);
            return g;
        };
        rowbuf[wave][lane] = pack8(a0, a1);                     // groups 0..63
        if (lane < 32) rowbuf[wave][64 + lane] = pack8(b0, b1); // groups 64..95
    }
    __syncthreads();

    // write-out: 384 pieces (12 chunks x 8 rows x 4 kgp); 32 consecutive
    // threads write 512 B contiguous (one chunk, 8 rows).
    int idx = threadIdx.x;
    if (idx < 384) {
        int c = idx >> 5, r = (idx >> 2) & 7, kgp = idx & 3;
        int pr = rg * 8 + r;
        if (pr < P) {
            int kg = kgp ^ ((pr >> 1) & 3);
            uint2 lo = rowbuf[r][c * 8 + kg];        // s=0 half
            uint2 hi = rowbuf[r][c * 8 + 4 + kg];    // s=1 half
            uint4 o; o.x = lo.x; o.y = lo.y; o.z = hi.x; o.w = hi.y;
            *(uint4*)(Y + (size_t)(img * NCH + c) * CHB + (pr * 4 + kgp) * 16) = o;
        }
    }
}

// ---------------------------------------------------------------------------
// Kernel 2 (control flow identical to HW-verified R6; dtype fp8): two blocks
// per pair (q-halves), 256 threads = 4 waves. Waves 0-2: 4 p-subtiles each;
// wave 3: 1 subtile (rows 192..207) -> 13 p-subtiles. Each b128 frag read
// feeds 2 x mfma_f32_16x16x32_fp8_fp8 (bf16 rate, half frag bytes ->
// LDS 662 cyc vs MFMA 883 cyc per block-chunk: MFMA-bound).
// Triple-buffered global_load_lds staging + raw s_barrier + manual
// s_waitcnt vmcnt(N): next chunk's DMAs stay in flight across the MFMA phase.
// ---------------------------------------------------------------------------
__global__ __launch_bounds__(256, 2) void pair_kernel(const unsigned char* __restrict__ Y,
                                                      float* __restrict__ out) {
    __shared__ uint4 tiles[3 * TPB];   // 64512 B (colmax aliased in epilogue)
    __shared__ float redp[4];

    int bx = blockIdx.x;
    int b  = bx >> 1;                // pair index
    int qh = bx & 1;                 // q-half
    int ia, ja; bool is_nn;
    if (b < 496) {
        is_nn = true;
        int i = 0, rem = b;
        while (rem >= 31 - i) { rem -= 31 - i; ++i; }   // triangular, i<j
        ia = i; ja = i + 1 + rem;
    } else {
        is_nn = false;
        int t = b - 496;
        ia = t & 31; ja = NN + (t >> 5);
    }

    int tid  = threadIdx.x;
    int lane = tid & 63;
    int wave = tid >> 6;             // 0..3
    int r16  = lane & 15;
    int quad = lane >> 4;            // 0..3 : k-group of 8
    int sw   = quad ^ ((r16 >> 1) & 3);   // XOR swizzle (verified conflict-free)

    // constant-offset frag base pointers (all further addressing is immediates)
    const char* abp = (const char*)tiles + wave * 4096 + (r16 * 4 + sw) * 16;
    const char* bbp = (const char*)tiles + APIECES * 16 + (r16 * 4 + sw) * 16;

    floatx4 acc[4][7];
    #pragma unroll
    for (int ps = 0; ps < 4; ++ps)
        #pragma unroll
        for (int t = 0; t < 7; ++t)
            acc[ps][t] = (floatx4){0.f, 0.f, 0.f, 0.f};

    // 21 DMA instrs/chunk: i<14 = A pieces, i>=14 = B-half pieces.
    // waves issue i = wave+4u (u<5) -> i 0..19; wave 0 also issues i=20.
    l_u8* lds0 = (l_u8*)&tiles[0];
    auto stage = [&](const unsigned char* ga, const unsigned char* gb, l_u8* ldsb) {
        #pragma unroll
        for (int u = 0; u < 5; ++u) {
            int i = wave + 4 * u;
            const unsigned char* g = (i < 14) ? ga + (i * 64 + lane) * 16
                                              : gb + ((i - 14) * 64 + lane) * 16;
            __builtin_amdgcn_global_load_lds((const g_u8*)g, ldsb + i * 1024, 16, 0, 0);
        }
        if (wave == 0)
            __builtin_amdgcn_global_load_lds((const g_u8*)(gb + (6 * 64 + lane) * 16),
                                             ldsb + 20 * 1024, 16, 0, 0);
    };

    const unsigned char* gA = Y + (size_t)ia * (NCH * CHB);
    const unsigned char* gB = Y + (size_t)ja * (NCH * CHB) + qh * (BPIECES * 16);
    stage(gA, gB, lds0);            gA += CHB; gB += CHB;
    stage(gA, gB, lds0 + BUFB);     gA += CHB; gB += CHB;

    for (int cb = 0; cb < NCH; cb += 3) {
        #pragma unroll
        for (int cc = 0; cc < 3; ++cc) {
            int c = cb + cc;
            // wait for chunk c's DMAs only (leave chunk c+1's in flight)
            if (c == NCH - 1)    __builtin_amdgcn_s_waitcnt(0xF70);  // vmcnt(0)
            else if (wave == 0)  __builtin_amdgcn_s_waitcnt(0xF76);  // vmcnt(6)
            else                 __builtin_amdgcn_s_waitcnt(0xF75);  // vmcnt(5)
            __builtin_amdgcn_s_barrier();
            __builtin_amdgcn_sched_barrier(0);   // pin: no ds_read above barrier

            longx2 afr[4], bfr[7];
            afr[0] = *(const longx2*)(abp + cc * BUFB);
            if (wave < 3) {
                afr[1] = *(const longx2*)(abp + cc * BUFB + 1024);
                afr[2] = *(const longx2*)(abp + cc * BUFB + 2048);
                afr[3] = *(const longx2*)(abp + cc * BUFB + 3072);
            }
            #pragma unroll
            for (int t = 0; t < 7; ++t)
                bfr[t] = *(const longx2*)(bbp + cc * BUFB + t * 1024);

            if (c + 2 < NCH) {
                stage(gA, gB, lds0 + ((cc + 2) % 3) * BUFB);
                gA += CHB; gB += CHB;
            }

            #pragma unroll
            for (int s = 0; s < 2; ++s) {        // two K=32 steps per chunk
                #pragma unroll
                for (int t = 0; t < 7; ++t)
                    acc[0][t] = __builtin_amdgcn_mfma_f32_16x16x32_fp8_fp8(
                        afr[0][s], bfr[t][s], acc[0][t], 0, 0, 0);
                if (wave < 3) {
                    #pragma unroll
                    for (int ps = 1; ps < 4; ++ps)
                        #pragma unroll
                        for (int t = 0; t < 7; ++t)
                            acc[ps][t] = __builtin_amdgcn_mfma_f32_16x16x32_fp8_fp8(
                                afr[ps][s], bfr[t][s], acc[ps][t], 0, 0, 0);
                }
            }
        }
    }

    __syncthreads();                 // all tile reads done; alias as colmax
    float* colmax = (float*)tiles;   // [4][112]

    // C/D: col q = lane&15, row p = quad*4 + r (within subtile)
    #pragma unroll
    for (int t = 0; t < 7; ++t) {
        float m = -3.0e38f;
        #pragma unroll
        for (int ps = 0; ps < 4; ++ps) {
            int pbase = wave * 64 + ps * 16 + quad * 4;
            #pragma unroll
            for (int r = 0; r < 4; ++r)
                if (pbase + r < P) m = fmaxf(m, acc[ps][t][r]);
        }
        m = fmaxf(m, __shfl_xor(m, 16));
        m = fmaxf(m, __shfl_xor(m, 32));
        if (quad == 0) colmax[wave * 112 + t * 16 + r16] = m;
    }
    __syncthreads();

    float contrib = 0.f;
    if (tid < 112 && qh * 112 + tid < P) {       // q >= 196 are pad cols
        float cm = fmaxf(fmaxf(colmax[tid], colmax[112 + tid]),
                         fmaxf(colmax[224 + tid], colmax[336 + tid]));
        contrib = is_nn ? (1.0f - cm) * (1.0f / (496.0f * 196.0f))
                        : fmaxf(cm - MARGIN, 0.0f) * (1.0f / (1024.0f * 196.0f));
    }
    #pragma unroll
    for (int o = 32; o > 0; o >>= 1) contrib += __shfl_down(contrib, o);
    if (lane == 0) redp[wave] = contrib;
    __syncthreads();
    if (tid == 0)
        atomicAdd(out, redp[0] + redp[1] + redp[2] + redp[3]);
}

// ---------------------------------------------------------------------------
extern "C" void kernel_launch(void* const* d_in, const int* in_sizes, int n_in,
                              void* d_out, int out_size, void* d_ws, size_t ws_size,
                              hipStream_t stream) {
    const float* nrm = (const float*)d_in[0];   // [32,196,768] fp32
    const float* dft = (const float*)d_in[1];   // [32,196,768] fp32
    float* out = (float*)d_out;                 // scalar fp32
    unsigned char* Y = (unsigned char*)d_ws;    // fp8 e4m3, [64][12][896] pieces = 10.5 MB

    norm_kernel<<<64 * 28, 512, 0, stream>>>(nrm, dft, Y, out);
    pair_kernel<<<2 * (496 + 1024), 256, 0, stream>>>(Y, out);
}